// Round 3
// baseline (244.183 us; speedup 1.0000x reference)
//
#include <hip/hip_runtime.h>
#include <math.h>

// ---------------- workspace layout (float offsets) ----------------
#define NHEAD     10004
#define OFF_HEAD  0        // 10004 head logits
#define OFF_H0    10004    // 960 projected floats (h0|h1|h2|h3 contiguous)
#define OFF_C0    10964    // 10000 cluster-0 logits
#define OFF_C1    20964    // 20000
#define OFF_C2    40964    // 40000
#define OFF_C3    80964    // 20000
#define OFF_P     100964   // per-unit exp partials (NUNITS floats)
#define OFF_CNT   117348   // block-done ticket counter (int), zeroed by proj

// ---- uniform 8KB units: head 2 rows | c0 4 | c1 8 | c2 16 | c3 32 ----
#define B_C0   5002        // head units [0,5002):     5002*2  = 10004
#define B_C1   7502        // c0 units [5002,7502):    2500*4  = 10000
#define B_C2   10002       // c1 units [7502,10002):   2500*8  = 20000
#define B_C3   12502       // c2 units [10002,12502):  2500*16 = 40000
#define NUNITS 13127       // c3 units [12502,13127):  625*32  = 20000
#define NBLK   768         // 3 blocks/CU — all co-resident at (256,3)
#define STRIDE 3072        // waves; units/wave = 4 or 5 (wid<839 -> 5)

__device__ __forceinline__ float wave_sum(float v) {
  v += __shfl_xor(v, 32, 64);
  v += __shfl_xor(v, 16, 64);
  v += __shfl_xor(v, 8, 64);
  v += __shfl_xor(v, 4, 64);
  v += __shfl_xor(v, 2, 64);
  v += __shfl_xor(v, 1, 64);
  return v;
}

__device__ __forceinline__ float dot4(float4 a, float4 c) {
  return a.x * c.x + a.y * c.y + a.z * c.z + a.w * c.w;
}

// Kernel A: 960 projection rows, 1 row/wave. Also zeroes the ticket counter.
__global__ __launch_bounds__(256) void proj_kernel(
    const float* __restrict__ feat,
    const float* __restrict__ p0, const float* __restrict__ p1,
    const float* __restrict__ p2, const float* __restrict__ p3,
    float* __restrict__ ws) {
  if (blockIdx.x == 0 && threadIdx.x == 0) ((int*)(ws + OFF_CNT))[0] = 0;
  __shared__ __align__(16) float sf[1024];
  ((float4*)sf)[threadIdx.x] = ((const float4*)feat)[threadIdx.x];
  __syncthreads();
  const float4* sf4 = (const float4*)sf;
  const int lane = threadIdx.x & 63;
  const int pr = blockIdx.x * 4 + (threadIdx.x >> 6);  // 0..959
  const float* src;
  if (pr < 512)      src = p0 + (size_t)pr * 1024;
  else if (pr < 768) src = p1 + (size_t)(pr - 512) * 1024;
  else if (pr < 896) src = p2 + (size_t)(pr - 768) * 1024;
  else               src = p3 + (size_t)(pr - 896) * 1024;
  const float4* src4 = (const float4*)src;
  float4 ld[4];
#pragma unroll
  for (int j = 0; j < 4; ++j) ld[j] = src4[lane + j * 64];
  float acc = 0.f;
#pragma unroll
  for (int j = 0; j < 4; ++j) acc += dot4(ld[j], sf4[lane + j * 64]);
  acc = wave_sum(acc);
  if (lane == 0) ws[NHEAD + pr] = acc;
}

// Every unit is one contiguous 8KB block: only the base differs by segment.
__device__ __forceinline__ const float4* unit_base(
    int u, const float* __restrict__ head_w, const float* __restrict__ w0,
    const float* __restrict__ w1, const float* __restrict__ w2,
    const float* __restrict__ w3) {
  const float* p; int v;
  if (u < B_C0)      { p = head_w; v = u; }
  else if (u < B_C1) { p = w0; v = u - B_C0; }
  else if (u < B_C2) { p = w1; v = u - B_C1; }
  else if (u < B_C3) { p = w2; v = u - B_C2; }
  else               { p = w3; v = u - B_C3; }
  return (const float4*)p + (size_t)v * 512;
}

#define UNIT_LOAD(u, dst) do {                                   \
    const float4* _bp = unit_base(u, head_w, w0, w1, w2, w3);    \
    _Pragma("unroll")                                            \
    for (int _j = 0; _j < 8; ++_j) dst[_j] = _bp[_j * 64 + lane];\
  } while (0)

__device__ __forceinline__ void unit_compute(
    int u, int lane, const float* sh, const float4* ld, float* __restrict__ ws) {
  float esum;
  if (u < B_C0) {                     // head: 2 rows, D=1024
    const float4* sf4 = (const float4*)sh;
    float a0 = 0.f, a1 = 0.f;
#pragma unroll
    for (int j = 0; j < 4; ++j) {
      a0 += dot4(ld[j], sf4[lane + j * 64]);
      a1 += dot4(ld[4 + j], sf4[lane + j * 64]);
    }
    a0 = wave_sum(a0); a1 = wave_sum(a1);
    if (lane == 0) { ws[OFF_HEAD + 2 * u] = a0; ws[OFF_HEAD + 2 * u + 1] = a1; }
    esum = expf(a0) + expf(a1);
  } else if (u < B_C1) {              // c0: 4 rows, h=512
    const float4* h4 = (const float4*)(sh + 1024);
    const float4 cv0 = h4[lane], cv1 = h4[lane + 64];
    const int r0 = (u - B_C0) * 4;
    esum = 0.f;
#pragma unroll
    for (int k = 0; k < 4; ++k) {
      float a = dot4(ld[2 * k], cv0) + dot4(ld[2 * k + 1], cv1);
      a = wave_sum(a);
      if (lane == 0) ws[OFF_C0 + r0 + k] = a;
      esum += expf(a);
    }
  } else if (u < B_C2) {              // c1: 8 rows, h=256
    const float4 cv = ((const float4*)(sh + 1536))[lane];
    const int r0 = (u - B_C1) * 8;
    esum = 0.f;
#pragma unroll
    for (int k = 0; k < 8; ++k) {
      float a = wave_sum(dot4(ld[k], cv));
      if (lane == 0) ws[OFF_C1 + r0 + k] = a;
      esum += expf(a);
    }
  } else if (u < B_C3) {              // c2: 16 rows, h=128, 2 rows/wave-load
    const float4 cv = ((const float4*)(sh + 1792))[lane & 31];
    const int r0 = (u - B_C2) * 16;
    esum = 0.f;
#pragma unroll
    for (int p = 0; p < 8; ++p) {
      float a = dot4(ld[p], cv);
      a += __shfl_xor(a, 1, 64);
      a += __shfl_xor(a, 2, 64);
      a += __shfl_xor(a, 4, 64);
      a += __shfl_xor(a, 8, 64);
      a += __shfl_xor(a, 16, 64);     // each 32-half holds its row sum
      if ((lane & 31) == 0) ws[OFF_C2 + r0 + 2 * p + (lane >> 5)] = a;
      esum += expf(a);
    }
    esum += __shfl_xor(esum, 32, 64);
  } else {                            // c3: 32 rows, h=64, 4 rows/wave-load
    const float4 cv = ((const float4*)(sh + 1920))[lane & 15];
    const int r0 = (u - B_C3) * 32;
    esum = 0.f;
#pragma unroll
    for (int p = 0; p < 8; ++p) {
      float a = dot4(ld[p], cv);
      a += __shfl_xor(a, 1, 64);
      a += __shfl_xor(a, 2, 64);
      a += __shfl_xor(a, 4, 64);
      a += __shfl_xor(a, 8, 64);      // each 16-group holds its row sum
      if ((lane & 15) == 0) ws[OFF_C3 + r0 + 4 * p + (lane >> 4)] = a;
      esum += expf(a);
    }
    esum += __shfl_xor(esum, 16, 64);
    esum += __shfl_xor(esum, 32, 64);
  }
  if (lane == 0) ws[OFF_P + u] = esum;
}

// Kernel B: 768 persistent blocks (all co-resident), 3072 waves, 4-5 units
// per wave with ping-pong A/B prefetch: loads for unit n+1 issued before
// computing unit n, so every wave keeps 8KB in flight continuously.
// Last block to finish runs the finalize inline (ticket pattern).
__global__ __launch_bounds__(256, 3) void main_kernel(
    const float* __restrict__ feat, const float* __restrict__ head_w,
    const float* __restrict__ w0, const float* __restrict__ w1,
    const float* __restrict__ w2, const float* __restrict__ w3,
    const int* __restrict__ targets, float* __restrict__ ws,
    float* __restrict__ out) {
  __shared__ __align__(16) float sh[1984];  // feat[1024] | proj[960]
  __shared__ float r5[4][5];
  __shared__ float slse[5];
  __shared__ int isLast;
  const int t = threadIdx.x;
  ((float4*)sh)[t] = ((const float4*)feat)[t];
  if (t < 240) ((float4*)(sh + 1024))[t] = ((const float4*)(ws + OFF_H0))[t];
  __syncthreads();
  const int lane = t & 63;
  const int wid = blockIdx.x * 4 + (t >> 6);

  float4 A[8], B[8];
  // wid < 3072: u0,u1,u2,u3 = wid+{0,3072,6144,9216} are ALWAYS < 13127.
  const int u0 = wid, u1 = wid + STRIDE, u2 = wid + 2 * STRIDE,
            u3 = wid + 3 * STRIDE, u4 = wid + 4 * STRIDE;
  UNIT_LOAD(u0, A);
  UNIT_LOAD(u1, B);
  unit_compute(u0, lane, sh, A, ws);
  UNIT_LOAD(u2, A);
  unit_compute(u1, lane, sh, B, ws);
  UNIT_LOAD(u3, B);
  unit_compute(u2, lane, sh, A, ws);
  if (u4 < NUNITS) {
    UNIT_LOAD(u4, A);
    unit_compute(u3, lane, sh, B, ws);
    unit_compute(u4, lane, sh, A, ws);
  } else {
    unit_compute(u3, lane, sh, B, ws);
  }

  // ---- ticket: release our stores, count this block done ----
  __threadfence();
  __syncthreads();
  if (t == 0) {
    int old = atomicAdd((int*)(ws + OFF_CNT), 1);
    isLast = (old == NBLK - 1);
  }
  __syncthreads();
  if (!isLast) return;
  __threadfence();  // acquire: all 768 blocks' stores now visible

  // ---- fused finalize (256 threads) ----
  const int wv = t >> 6;
  float a0 = 0.f, a1 = 0.f, a2 = 0.f, a3 = 0.f, a4 = 0.f;
#pragma unroll 4
  for (int it = 0; it < 52; ++it) {
    int i = t + it * 256;
    if (i < NUNITS) {
      float v = ws[OFF_P + i];
      if (i < B_C0)      a0 += v;
      else if (i < B_C1) a1 += v;
      else if (i < B_C2) a2 += v;
      else if (i < B_C3) a3 += v;
      else               a4 += v;
    }
  }
  a0 = wave_sum(a0); a1 = wave_sum(a1); a2 = wave_sum(a2);
  a3 = wave_sum(a3); a4 = wave_sum(a4);
  if (lane == 0) { r5[wv][0] = a0; r5[wv][1] = a1; r5[wv][2] = a2; r5[wv][3] = a3; r5[wv][4] = a4; }
  __syncthreads();
  if (t < 5) {
    slse[t] = logf(r5[0][t] + r5[1][t] + r5[2][t] + r5[3][t]);
  }
  __syncthreads();
  const float lse0 = slse[0], lse1 = slse[1], lse2 = slse[2], lse3 = slse[3], lse4 = slse[4];
  const float g0 = ws[10000] - lse0, g1 = ws[10001] - lse0;
  const float g2 = ws[10002] - lse0, g3 = ws[10003] - lse0;
  float s = 0.f;
#pragma unroll 4
  for (int it = 0; it < 16; ++it) {
    int tgt = targets[t + it * 256];
    int addr = tgt + ((tgt >= 10000) ? 964 : 0);   // layout: all clusters at +964
    float lp = ws[addr];
    int e = (tgt >= 10000) + (tgt >= 20000) + (tgt >= 40000) + (tgt >= 80000);
    float lseS = (e == 0) ? lse0 : (e == 1) ? lse1 : (e == 2) ? lse2 : (e == 3) ? lse3 : lse4;
    float gS   = (e == 0) ? 0.f  : (e == 1) ? g0   : (e == 2) ? g1   : (e == 3) ? g2   : g3;
    s += lp - lseS + gS;
  }
  s = wave_sum(s);
  if (lane == 0) r5[wv][0] = s;
  __syncthreads();
  if (t == 0)
    out[0] = -(r5[0][0] + r5[1][0] + r5[2][0] + r5[3][0]) * (1.f / 4096.f);
}

extern "C" void kernel_launch(void* const* d_in, const int* in_sizes, int n_in,
                              void* d_out, int out_size, void* d_ws, size_t ws_size,
                              hipStream_t stream) {
  const float* feat    = (const float*)d_in[0];
  const int*   targets = (const int*)d_in[1];
  const float* head_w  = (const float*)d_in[2];
  const float* t0p = (const float*)d_in[3];
  const float* t0w = (const float*)d_in[4];
  const float* t1p = (const float*)d_in[5];
  const float* t1w = (const float*)d_in[6];
  const float* t2p = (const float*)d_in[7];
  const float* t2w = (const float*)d_in[8];
  const float* t3p = (const float*)d_in[9];
  const float* t3w = (const float*)d_in[10];
  float* ws  = (float*)d_ws;
  float* out = (float*)d_out;

  proj_kernel<<<240, 256, 0, stream>>>(feat, t0p, t1p, t2p, t3p, ws);
  main_kernel<<<NBLK, 256, 0, stream>>>(feat, head_w, t0w, t1w, t2w, t3w,
                                        targets, ws, out);
}